// Round 2
// 8623.843 us; speedup vs baseline: 1.0522x; 1.0522x over previous
//
#include <hip/hip_runtime.h>
#include <math.h>

// GRU: B=64, S=512, I=256, H=1024, O=256.
// Round 5: round-4 structure (flag-array barrier, 16B transpose-exchange)
// with the exchange READS made compiler-safe:
//   - Round 4 failed (absmax 0.79) because inline-asm loads with a deferred
//     manual vmcnt drain let the register allocator spill/copy the asm output
//     regs BEFORE the load completed (compiler sees asm as instantaneous).
//   - Fix: after waitflags, one agent-acquire fence (buffer_inv — the proven
//     round-3 read path), then PLAIN loads into a bf8[32] array. Compiler
//     owns the vmcnt bookkeeping; still issues a deep burst (one LLC round
//     trip), unlike round-3's shallow unroll-4 pipeline.
//   - x-part loads are issued BEFORE waitflags, so their values are already
//     in registers when buffer_inv runs; weights live in LDS (unaffected).
//   - Exchange writes stay sc0sc1 write-through (visible at LLC cross-XCD),
//     drained (vmcnt) before the per-block flag is posted.

#define KP 1288   // LDS K-stride (elems): 2576 B, 16B aligned

typedef __attribute__((ext_vector_type(8))) short bf8;
typedef __attribute__((ext_vector_type(4))) short bf4;
typedef __attribute__((ext_vector_type(4))) float f32x4;

__device__ __forceinline__ short f2b(float f) {
  unsigned u = __builtin_bit_cast(unsigned, f);
  u += 0x7fffu + ((u >> 16) & 1u);          // RNE
  return (short)(u >> 16);
}
__device__ __forceinline__ float sigm(float x) { return 1.f / (1.f + __expf(-x)); }
__device__ __forceinline__ float tanh_(float x) {
  float t = fminf(fmaxf(x, -12.f), 12.f);
  float e = __expf(2.f * t);
  return (e - 1.f) / (e + 1.f);
}

// ---- LLC write-through stores (bypass per-XCD L2; coherence point) ----
__device__ __forceinline__ void st_b128_llc(short* p, bf8 v) {
  asm volatile("global_store_dwordx4 %0, %1, off sc0 sc1"
               :: "v"(p), "v"(v) : "memory");
}
__device__ __forceinline__ void st_f32_llc(float* p, float v) {
  asm volatile("global_store_dword %0, %1, off sc0 sc1"
               :: "v"(p), "v"(v) : "memory");
}
__device__ __forceinline__ void st_i32_llc(int* p, int v) {
  asm volatile("global_store_dword %0, %1, off sc0 sc1"
               :: "v"(p), "v"(v) : "memory");
}
__device__ __forceinline__ void drain_vm() {
  asm volatile("s_waitcnt vmcnt(0)" ::: "memory");
}
__device__ __forceinline__ void acq() {
  __builtin_amdgcn_fence(__ATOMIC_ACQUIRE, "agent");   // buffer_inv
}
// lane L watches flag[L]; exit when all 64 block flags >= p.
// Load + waitcnt are INSIDE one asm block => value valid when asm retires.
__device__ __forceinline__ void waitflags(const int* flags, int p, int lane) {
  const int* fp = flags + lane;
  for (;;) {
    int f;
    asm volatile("global_load_dword %0, %1, off sc0 sc1\n"
                 "s_waitcnt vmcnt(0)"
                 : "=v"(f) : "v"(fp) : "memory");
    if (__all(f >= p)) break;
    __builtin_amdgcn_s_sleep(1);
  }
}

#define MFMA __builtin_amdgcn_mfma_f32_16x16x32_bf16

// ---------------- preprocessing ----------------

__global__ __launch_bounds__(256) void cvt_x(const float* __restrict__ in,
                                             short* __restrict__ outp) {
  int idx = blockIdx.x * 256 + threadIdx.x;        // 8192 blocks, 4 floats each
  float4 v = ((const float4*)in)[idx];
  bf4 o;
  o[0] = f2b(v.x); o[1] = f2b(v.y); o[2] = f2b(v.z); o[3] = f2b(v.w);
  ((bf4*)outp)[idx] = o;
}

// Wt[g][j][k] = bf16( k<1024 ? Wh_g[k][j] : Wx_g[k-1024][j] ), k=0..1279.
__global__ __launch_bounds__(256) void pack_w(
    const float* __restrict__ Whz, const float* __restrict__ Wxz,
    const float* __restrict__ Whr, const float* __restrict__ Wxr,
    const float* __restrict__ Whh, const float* __restrict__ Wxh,
    short* __restrict__ Wt) {
  int b = blockIdx.x;
  int g = b / 320, rem = b % 320;
  int jt = rem / 20, kt = rem % 20;
  int j0 = jt * 64, k0 = kt * 64;
  const float* Wh = (g == 0) ? Whz : (g == 1) ? Whr : Whh;
  const float* Wx = (g == 0) ? Wxz : (g == 1) ? Wxr : Wxh;
  __shared__ short tile[64 * 72];
  int tid = threadIdx.x;
  for (int p = 0; p < 16; ++p) {
    int r = p * 4 + (tid >> 6);
    int cc = tid & 63;
    int k = k0 + r;
    float v = (k < 1024) ? Wh[(size_t)k * 1024 + j0 + cc]
                         : Wx[(size_t)(k - 1024) * 1024 + j0 + cc];
    tile[r * 72 + cc] = f2b(v);
  }
  __syncthreads();
  int j = tid >> 2, kq = tid & 3;
  bf8 v0, v1;
#pragma unroll
  for (int i = 0; i < 8; ++i) {
    v0[i] = tile[(kq * 16 + i) * 72 + j];
    v1[i] = tile[(kq * 16 + 8 + i) * 72 + j];
  }
  short* dst = Wt + ((size_t)(g * 1024 + j0 + j)) * 1280 + k0 + kq * 16;
  *(bf8*)dst = v0;
  *((bf8*)dst + 1) = v1;
}

// ---------------- persistent GRU kernel ----------------
__global__ __launch_bounds__(256, 1) void gru_persistent(
    const short* __restrict__ xx,   // x bf16 [64][512][256]
    const short* __restrict__ Wt,   // packed weights bf16 [3][1024][1280]
    float* __restrict__ h32,        // fp32 h final [64][1024] (written s=511)
    short* __restrict__ h16,        // bf16 h (exchange)
    short* __restrict__ ab,         // bf16 r*h (exchange)
    int* __restrict__ flags,        // 64 per-block progress flags
    const float* __restrict__ bz, const float* __restrict__ br,
    const float* __restrict__ bh,
    const float* __restrict__ Wf, const float* __restrict__ bfv,
    float* __restrict__ out) {
  extern __shared__ short lds[];                 // 48*KP weights + 4*256 scratch

  const int tid = threadIdx.x;
  const int w = tid >> 6, lane = tid & 63;
  const int row16 = lane & 15, quad = lane >> 4;
  const int j0 = blockIdx.x * 16;
  const int bg0 = w * 16;
  const int bA = bg0 + row16;                    // batch row for A-loads

  const float bzv = bz[j0 + row16];
  const float brv = br[j0 + row16];
  const float bhv = bh[j0 + row16];

  // weights -> LDS (48 cols x 1280, transposed, bf16)
  for (int ch = tid; ch < 48 * 160; ch += 256) {
    int lc = ch / 160, c8 = ch % 160;
    int g = lc >> 4, j = j0 + (lc & 15);
    *(bf8*)(lds + lc * KP + c8 * 8) =
        *(const bf8*)(Wt + ((size_t)(g * 1024 + j)) * 1280 + c8 * 8);
  }
  __syncthreads();

  const short* wzp = lds + row16 * KP;
  const short* wrp = lds + (16 + row16) * KP;
  const short* wnp = lds + (32 + row16) * KP;
  short* sc = lds + 48 * KP + w * 256;           // 16x16 bf16 transpose tile
  const int ko = quad * 8;

  float hreg[4] = {0.f, 0.f, 0.f, 0.f};          // fp32 h, lives in regs
  float zreg[4];

  for (int s = 0; s < 512; ++s) {
    const short* xrow = xx + (bA * 512 + s) * 256 - 1024;  // +k valid k>=1024

    // ---------- phase 1: z, r ----------
    f32x4 az0 = {0.f,0.f,0.f,0.f}, az1 = {0.f,0.f,0.f,0.f};
    f32x4 ar0 = {0.f,0.f,0.f,0.f}, ar1 = {0.f,0.f,0.f,0.f};
    // x-part (independent of exchange) — in registers before the fence
#pragma unroll
    for (int kt = 32; kt < 40; ++kt) {
      int k = kt * 32 + ko;
      bf8 a = *(const bf8*)(xrow + k);
      az0 = MFMA(a, *(const bf8*)(wzp + k), az0, 0, 0, 0);
      ar0 = MFMA(a, *(const bf8*)(wrp + k), ar0, 0, 0, 0);
    }
    waitflags(flags, 2 * s, lane);               // all h16(s-1) at LLC
    acq();                                       // discard stale L1/L2 lines
    {
      const short* hb = h16 + bA * 1024 + ko;
      bf8 a[32];
#pragma unroll
      for (int t = 0; t < 32; ++t) a[t] = *(const bf8*)(hb + t * 32);
#pragma unroll
      for (int t = 0; t < 32; t += 2) {
        int k0 = t * 32 + ko, k1 = k0 + 32;
        az0 = MFMA(a[t],     *(const bf8*)(wzp + k0), az0, 0, 0, 0);
        az1 = MFMA(a[t + 1], *(const bf8*)(wzp + k1), az1, 0, 0, 0);
        ar0 = MFMA(a[t],     *(const bf8*)(wrp + k0), ar0, 0, 0, 0);
        ar1 = MFMA(a[t + 1], *(const bf8*)(wrp + k1), ar1, 0, 0, 0);
      }
    }
    f32x4 azs = az0 + az1, ars = ar0 + ar1;
#pragma unroll
    for (int i = 0; i < 4; ++i) {
      zreg[i] = sigm(azs[i] + bzv);
      float r = sigm(ars[i] + brv);
      sc[(quad * 4 + i) * 16 + row16] = f2b(r * hreg[i]);  // transpose via LDS
    }
    __syncthreads();
    if (lane < 32) {
      int rr = lane >> 1, hh = lane & 1;
      bf8 v = *(const bf8*)(sc + rr * 16 + hh * 8);
      st_b128_llc(ab + (bg0 + rr) * 1024 + j0 + hh * 8, v);
      drain_vm();                                // data at LLC before flag
    }
    __syncthreads();
    if (tid == 0) st_i32_llc(flags + blockIdx.x, 2 * s + 1);

    // ---------- phase 2: n, h update ----------
    f32x4 an0 = {0.f,0.f,0.f,0.f}, an1 = {0.f,0.f,0.f,0.f};
#pragma unroll
    for (int kt = 32; kt < 40; ++kt) {
      int k = kt * 32 + ko;
      bf8 a = *(const bf8*)(xrow + k);
      an0 = MFMA(a, *(const bf8*)(wnp + k), an0, 0, 0, 0);
    }
    waitflags(flags, 2 * s + 1, lane);           // all ab(s) at LLC
    acq();
    {
      const short* abb = ab + bA * 1024 + ko;
      bf8 a[32];
#pragma unroll
      for (int t = 0; t < 32; ++t) a[t] = *(const bf8*)(abb + t * 32);
#pragma unroll
      for (int t = 0; t < 32; t += 2) {
        int k0 = t * 32 + ko, k1 = k0 + 32;
        an0 = MFMA(a[t],     *(const bf8*)(wnp + k0), an0, 0, 0, 0);
        an1 = MFMA(a[t + 1], *(const bf8*)(wnp + k1), an1, 0, 0, 0);
      }
    }
    f32x4 ans = an0 + an1;
#pragma unroll
    for (int i = 0; i < 4; ++i) {
      float n = tanh_(ans[i] + bhv);
      hreg[i] = fmaf(zreg[i], n - hreg[i], hreg[i]);   // (1-z)h + z*n
      sc[(quad * 4 + i) * 16 + row16] = f2b(hreg[i]);
      if (s == 511)
        st_f32_llc(&h32[(bg0 + quad * 4 + i) * 1024 + j0 + row16], hreg[i]);
    }
    __syncthreads();
    if (lane < 32) {
      int rr = lane >> 1, hh = lane & 1;
      bf8 v = *(const bf8*)(sc + rr * 16 + hh * 8);
      st_b128_llc(h16 + (bg0 + rr) * 1024 + j0 + hh * 8, v);
      drain_vm();
    }
    __syncthreads();
    if (tid == 0) st_i32_llc(flags + blockIdx.x, 2 * s + 2);
  }

  // ---------- head: out[b][o] = sum_k h32[b][k]*Wf[k][o] + bf[o] ----------
  waitflags(flags, 1024, lane);
  acq();
  {
    const float* hrow = h32 + blockIdx.x * 1024;
    float acc = bfv[tid];
#pragma unroll 8
    for (int k = 0; k < 1024; ++k)
      acc = fmaf(hrow[k], Wf[(size_t)k * 256 + tid], acc);
    out[blockIdx.x * 256 + tid] = acc;
  }
}

// ---------------- host ----------------
extern "C" void kernel_launch(void* const* d_in, const int* in_sizes, int n_in,
                              void* d_out, int out_size, void* d_ws, size_t ws_size,
                              hipStream_t stream) {
  const float* x   = (const float*)d_in[0];
  const float* Wxz = (const float*)d_in[1];
  const float* Whz = (const float*)d_in[2];
  const float* Wxr = (const float*)d_in[3];
  const float* Whr = (const float*)d_in[4];
  const float* Wxh = (const float*)d_in[5];
  const float* Whh = (const float*)d_in[6];
  const float* bz  = (const float*)d_in[7];
  const float* br  = (const float*)d_in[8];
  const float* bh  = (const float*)d_in[9];
  const float* Wf  = (const float*)d_in[10];
  const float* bfp = (const float*)d_in[11];
  float* out = (float*)d_out;

  char* ws = (char*)d_ws;
  float* h32 = (float*)(ws + 0);            // 256 KB
  short* h16 = (short*)(ws + 262144);       // 128 KB
  int*   flg = (int*)  (ws + 393216);       // 4 KB (64 flags used)
  short* ab  = (short*)(ws + 397312);       // 128 KB
  short* xx  = (short*)(ws + 528384);       // 16 MB
  short* Wt  = (short*)(ws + 17305600);     // 7.86 MB (total ~24 MB)

  hipMemsetAsync(d_ws, 0, 397312, stream);  // h32 + h16 + flags = zeros

  cvt_x<<<8192, 256, 0, stream>>>(x, xx);
  pack_w<<<960, 256, 0, stream>>>(Whz, Wxz, Whr, Wxr, Whh, Wxh, Wt);

  const int smem = (48 * KP + 4 * 256) * 2; // 125,696 B
  hipFuncSetAttribute((const void*)gru_persistent,
                      hipFuncAttributeMaxDynamicSharedMemorySize, smem);
  void* args[] = {&xx, &Wt, &h32, &h16, &ab, &flg,
                  (void*)&bz, (void*)&br, (void*)&bh, (void*)&Wf, (void*)&bfp, &out};
  hipLaunchCooperativeKernel((const void*)gru_persistent, dim3(64), dim3(256),
                             args, smem, stream);
}